// Round 14
// baseline (1553.425 us; speedup 1.0000x reference)
//
#include <hip/hip_runtime.h>
#include <hip/hip_bf16.h>
#include <stdint.h>

// ---------------------------------------------------------------------------
// MixModel (MI355X / gfx950), round 14: UNFUSED layered design.
//
// r10-r13 lesson: the fused-persistent kernel needs 162 VGPRs of message state
// per wave; the compiler either runs 1 wave/SIMD (latency-bound, 734us) or
// splits 128/128 and scratch-spills (slower). So: materialize messages in d_ws
// (65536 x 81 x 32B = 170MB, L3-scale) and run 6 thin layer kernels + common.
//  - layer_step: grid (Bt/256, 9 positions), 576 thr = 9 waves (wave = j-tile).
//    A-frags (6 x f16x8 = 24 VGPR) loaded once from the r10-proven K16 panel
//    layout; B-chunks (12 x 8B/lane) loaded coalesced from ws; double-buffered
//    across 16-sample tiles with one barrier/tile (in-block read-before-write;
//    cross-block safety via column/row parity ownership - no double buffer).
//  - in-place parity: even layer (P=0) position o reads cells (i*9+o), writes
//    (j*9+o); odd reads (o*9+i), writes (o*9+j). After d=5 cells are canonical
//    (src*9+dst) for the common layer.
//  - common_unf: block per M-tile, panel in LDS, streams msg rows; policy to
//    out, raw wdl-hidden to ws; wdl_final applies relu + 64x3 matmul.
//  - Fallback: if ws_size < WS_NEED, run the proven r10 fused kernel.
// ---------------------------------------------------------------------------

typedef __attribute__((ext_vector_type(4))) float    f32x4;
typedef __attribute__((ext_vector_type(4))) _Float16 f16x4;
typedef __attribute__((ext_vector_type(8))) _Float16 f16x8;
typedef unsigned long long u64;
typedef unsigned int u32;

#define STEP_BYTES 55296            // 9 jt * 6 slices * 64 lanes * 16B
#define PHA_SZ     30720            // fused path: jt 0..4
#define PHB_SZ     24576            // fused path: jt 5..8
#define CMN_STRIDE 41472            // 9 i * (4*1024 + 512)
#define CPA_SZ     23040            // fused path: i 0..4
#define CPB_SZ     18432            // fused path: i 5..8
#define WS_LAYER   (54*STEP_BYTES)  // 2,985,984
#define LDS_TOTAL  (2*PHA_SZ)       // 61,440 (fused path)

__device__ __forceinline__ unsigned short f2h(float f) {
  return __builtin_bit_cast(unsigned short, (_Float16)f);
}
__device__ __forceinline__ u64 as_u64(f16x4 v) { return __builtin_bit_cast(u64, v); }
__device__ __forceinline__ f16x4 as_f16x4(u64 v) { return __builtin_bit_cast(f16x4, v); }

__device__ __forceinline__ f32x4 mfma16(f16x4 a, f16x4 b, f32x4 c) {
#if __has_builtin(__builtin_amdgcn_mfma_f32_16x16x16f16)
  return __builtin_amdgcn_mfma_f32_16x16x16f16(a, b, c, 0, 0, 0);
#else
  asm("v_mfma_f32_16x16x16_f16 %0, %1, %2, %0" : "+v"(c) : "v"(a), "v"(b));
  return c;
#endif
}

// static feature value for (sample b, position o, padded k-index kidx in [0,48))
__device__ __forceinline__ float static_feat(const float* __restrict__ mask,
                                             const float* __restrict__ board,
                                             int b, int o, int kidx) {
  if (kidx < 9)  return mask [b*81  + o*9 + kidx];
  if (kidx < 18) return board[b*180 +       o*9 + (kidx - 9)];
  if (kidx < 27) return board[b*180 + 90 +  o*9 + (kidx - 18)];
  if (kidx < 36) return board[b*180 +       81 + (kidx - 27)];
  if (kidx < 45) return board[b*180 + 90 +  81 + (kidx - 36)];
  return 0.f;
}

// async stage nbytes (16B-granular) into LDS across 256 threads
__device__ __forceinline__ void stage_bytes(const unsigned char* __restrict__ src,
                                            unsigned char* dstlds, int nbytes, int tid) {
  const int n16 = nbytes / 16;
  const int ubase = tid & ~63;
  for (int k = 0; k * 256 < n16; ++k) {
    const int idx = k * 256 + tid;
    if (idx < n16) {
      __builtin_amdgcn_global_load_lds(
          (const __attribute__((address_space(1))) void*)(src + (size_t)idx * 16),
          (__attribute__((address_space(3))) void*)(dstlds + (size_t)(k * 256 + ubase) * 16),
          16, 0, 0);
    }
  }
}

// ===========================================================================
// UNFUSED PATH
// ===========================================================================

// ---- B-chunk loads for one 16-sample tile (coalesced: 512B/chunk/wave) -----
template<int P, int FIRST>
__device__ __forceinline__ void load_B(u64 (&B)[12],
    const unsigned char* __restrict__ stat, const unsigned char* __restrict__ msg,
    int o, int b0, int s15, int hq, int Bt)
{
  const size_t lo = (size_t)(b0 + s15) * 32 + (size_t)hq * 8;
  B[0] = *(const u64*)(stat + ((size_t)(o * 2 + 0) * Bt) * 32 + lo);
  B[1] = *(const u64*)(stat + ((size_t)(o * 2 + 1) * Bt) * 32 + lo);
  B[2] = *(const u64*)(stat + ((size_t)18 * Bt) * 32 + lo);
  if (!FIRST) {
#pragma unroll
    for (int i = 0; i < 9; ++i) {
      const int cell = P ? (o * 9 + i) : (i * 9 + o);
      B[3 + i] = *(const u64*)(msg + ((size_t)cell * Bt) * 32 + lo);
    }
  }
}

// ---- compute one j-tile (12 or 3 K16 MFMAs) + store message chunk ----------
template<int P, int FIRST>
__device__ __forceinline__ void comp_store(const f16x8 (&af)[6], const u64 (&B)[12],
    unsigned char* __restrict__ msg, int o, int j, int b0, int s15, int hq, int Bt)
{
  f32x4 acc = 0.f;
#pragma unroll
  for (int s = 0; s < (FIRST ? 2 : 6); ++s) {
    const f16x4 alo = __builtin_shufflevector(af[s], af[s], 0, 1, 2, 3);
    acc = mfma16(alo, as_f16x4(B[2 * s]), acc);
    if (!FIRST || s == 0) {
      const f16x4 ahi = __builtin_shufflevector(af[s], af[s], 4, 5, 6, 7);
      acc = mfma16(ahi, as_f16x4(B[2 * s + 1]), acc);
    }
  }
  f16x4 h;
#pragma unroll
  for (int r = 0; r < 4; ++r)
    h[r] = (_Float16)fmaxf(acc[r], 0.f);
  const int wcell = P ? (o * 9 + j) : (j * 9 + o);
  *(u64*)(msg + ((size_t)wcell * Bt) * 32 + (size_t)(b0 + s15) * 32 + (size_t)hq * 8)
      = as_u64(h);
}

// ---- one layer: grid (Bt/256, 9). 576 thr = 9 waves, wave = output j-tile --
template<int P, int FIRST>
__global__ __launch_bounds__(576, 4) void layer_step(
    const unsigned char* __restrict__ wsLW, const unsigned char* __restrict__ stat,
    unsigned char* __restrict__ msg, int d, int Bt)
{
  const int tid = threadIdx.x;
  const int lane = tid & 63;
  const int j = tid >> 6;            // this wave's output tile
  const int o = blockIdx.y;
  const int s15 = lane & 15, hq = lane >> 4;

  // A fragments for (d, o, j): 6 slices x 16B/lane (r10-proven K16 panel)
  const unsigned char* panel = wsLW + ((size_t)(d * 9 + o)) * STEP_BYTES
                               + (size_t)j * 6144 + (size_t)lane * 16;
  f16x8 af[6];
#pragma unroll
  for (int s = 0; s < 6; ++s)
    af[s] = *(const f16x8*)(panel + s * 1024);

  int b0 = blockIdx.x * 256;   // 16 tiles of 16 samples
  u64 B0[12], B1[12];
  load_B<P, FIRST>(B0, stat, msg, o, b0, s15, hq, Bt);
#pragma unroll 1
  for (int t = 0; t < 16; t += 2) {
    asm volatile("s_waitcnt vmcnt(0)" ::: "memory");
    __syncthreads();                               // all reads of tile t done
    if (t + 1 < 16) load_B<P, FIRST>(B1, stat, msg, o, b0 + 16, s15, hq, Bt);
    comp_store<P, FIRST>(af, B0, msg, o, j, b0, s15, hq, Bt);
    asm volatile("s_waitcnt vmcnt(0)" ::: "memory");
    __syncthreads();
    if (t + 2 < 16) load_B<P, FIRST>(B0, stat, msg, o, b0 + 32, s15, hq, Bt);
    comp_store<P, FIRST>(af, B1, msg, o, j, b0 + 16, s15, hq, Bt);
    b0 += 32;
  }
}

// ---- common layer: grid (Bt/1024, 10 mt), 256 thr, panel in LDS ------------
__global__ __launch_bounds__(256, 4) void common_unf(
    const unsigned char* __restrict__ wsCW, const unsigned char* __restrict__ msg,
    const float* __restrict__ common_b, float* __restrict__ wdlbuf,
    float* __restrict__ out, int Bt)
{
  extern __shared__ unsigned char lds[];
  const int tid = threadIdx.x;
  const int lane = tid & 63;
  const int wid = tid >> 6;
  const int s15 = lane & 15, hq = lane >> 4;
  const int mt = blockIdx.y;

  stage_bytes(wsCW + (size_t)mt * CMN_STRIDE, lds, CMN_STRIDE, tid);
  asm volatile("s_waitcnt vmcnt(0)" ::: "memory");
  __syncthreads();

  const int tile0 = (blockIdx.x * 4 + wid) * 16;   // 16 tiles per wave
  for (int tt = 0; tt < 16; ++tt) {
    const int b0 = (tile0 + tt) * 16;
    const size_t lo = (size_t)(b0 + s15) * 32 + (size_t)hq * 8;
    f32x4 acc = 0.f;
#pragma unroll
    for (int i = 0; i < 9; ++i) {
      u64 m[9];
#pragma unroll
      for (int jj = 0; jj < 9; ++jj)
        m[jj] = *(const u64*)(msg + ((size_t)(i * 9 + jj) * Bt) * 32 + lo);
      const unsigned char* base = lds + i * 4608;
#pragma unroll
      for (int p = 0; p < 4; ++p) {
        const f16x8 a8 = *(const f16x8*)(base + p * 1024 + (size_t)lane * 16);
        const f16x4 alo = __builtin_shufflevector(a8, a8, 0, 1, 2, 3);
        const f16x4 ahi = __builtin_shufflevector(a8, a8, 4, 5, 6, 7);
        acc = mfma16(alo, as_f16x4(m[2 * p]),     acc);
        acc = mfma16(ahi, as_f16x4(m[2 * p + 1]), acc);
      }
      const f16x4 al = *(const f16x4*)(base + 4096 + (size_t)lane * 8);
      acc = mfma16(al, as_f16x4(m[8]), acc);
    }
#pragma unroll
    for (int r = 0; r < 4; ++r) {
      const int c = mt * 16 + 4 * hq + r;
      if (c < 145) {
        const float v = acc[r] + common_b[c];
        if (c < 81) out[(size_t)3 * Bt + (size_t)(b0 + s15) * 81 + c] = v;
        else        wdlbuf[(size_t)(c - 81) * Bt + (b0 + s15)] = v;  // raw
      }
    }
  }
}

// ---- wdl head: out[b] = relu(hidden) @ wdl_w + wdl_b -----------------------
__global__ __launch_bounds__(256) void wdl_final(
    const float* __restrict__ wdlbuf, const float* __restrict__ wdl_w,
    const float* __restrict__ wdl_b, float* __restrict__ out, int Bt)
{
  const int b = blockIdx.x * 256 + threadIdx.x;
  if (b >= Bt) return;
  float s0 = wdl_b[0], s1 = wdl_b[1], s2 = wdl_b[2];
  for (int cc = 0; cc < 64; ++cc) {
    const float h = fmaxf(wdlbuf[(size_t)cc * Bt + b], 0.f);
    s0 += h * wdl_w[cc * 3 + 0];
    s1 += h * wdl_w[cc * 3 + 1];
    s2 += h * wdl_w[cc * 3 + 2];
  }
  out[(size_t)b * 3 + 0] = s0;
  out[(size_t)b * 3 + 1] = s1;
  out[(size_t)b * 3 + 2] = s2;
}

// ---- prologue: pack static features -> B-chunk layout ----------------------
// slot: 0..17 = (o, chunk0/1), 18 = chunk2 (o-independent, k=45 -> 1.0)
// addr = (slot*Bt + b)*32 + hq*8 ; value kidx = c*16 + 4*hq + e.
__global__ __launch_bounds__(256) void conv_static(
    const float* __restrict__ mask, const float* __restrict__ board,
    unsigned char* __restrict__ stat, int Bt)
{
  const int gid = blockIdx.x * 256 + threadIdx.x;   // (slot, b, hq)
  if (gid >= 19 * Bt * 4) return;
  const int hq = gid & 3;
  const int b = (gid >> 2) % Bt;
  const int slot = gid / (Bt * 4);
  const int o = (slot < 18) ? (slot >> 1) : 0;
  const int c = (slot < 18) ? (slot & 1) : 2;
  unsigned short v[4];
#pragma unroll
  for (int e = 0; e < 4; ++e) {
    const int kidx = c * 16 + 4 * hq + e;
    v[e] = f2h((kidx == 45) ? 1.f : static_feat(mask, board, b, o, kidx));
  }
  const u32 w0 = (u32)v[0] | ((u32)v[1] << 16);
  const u32 w1 = (u32)v[2] | ((u32)v[3] << 16);
  *(uint2*)(stat + (size_t)gid * 8) = make_uint2(w0, w1);
}

// ===========================================================================
// FUSED FALLBACK PATH (r10, proven 734us) — used when ws_size < WS_NEED
// ===========================================================================

template<int P, int O, int J0, int J1, int OFF>
__device__ __forceinline__ void jt_range(const unsigned char* __restrict__ buf,
    u64 (&msg)[9][9], const u64 (&msgc)[9], f16x4 st0, f16x4 st1, f16x4 stc, int lane)
{
  const unsigned char* abase = buf + (size_t)lane * 16 - OFF;
#pragma unroll
  for (int j = J0; j < J1; ++j) {
    f32x4 acc = 0.f;
#pragma unroll
    for (int sp = 0; sp < 6; ++sp) {
      const f16x8 af = *(const f16x8*)(abase + j * 6144 + sp * 1024);
      const f16x4 alo = __builtin_shufflevector(af, af, 0, 1, 2, 3);
      const f16x4 ahi = __builtin_shufflevector(af, af, 4, 5, 6, 7);
      const int c0 = 2 * sp, c1 = 2 * sp + 1;
      if (c0 == 0)      acc = mfma16(alo, st0, acc);
      else if (c0 == 2) acc = mfma16(alo, stc, acc);
      else              acc = mfma16(alo, as_f16x4(msgc[c0 - 3]), acc);
      if (c1 == 1)      acc = mfma16(ahi, st1, acc);
      else              acc = mfma16(ahi, as_f16x4(msgc[c1 - 3]), acc);
    }
    f16x4 h;
#pragma unroll
    for (int r = 0; r < 4; ++r)
      h[r] = (_Float16)fmaxf(acc[r], 0.f);
    if (P) msg[O][j] = as_u64(h); else msg[j][O] = as_u64(h);
  }
}

template<int P, int O>
__device__ __forceinline__ void do_step_layer(int base, const unsigned char* __restrict__ ws,
    unsigned char* bufA, unsigned char* bufB, u64 (&msg)[9][9],
    u64 sb, u32 sb8, f16x4 stc, int lane, int tid)
{
  const int step = base + P * 9 + O;
  asm volatile("s_waitcnt vmcnt(0)" ::: "memory");
  __syncthreads();
  stage_bytes(ws + (size_t)step * STEP_BYTES + PHA_SZ, bufB, PHB_SZ, tid);
  f16x4 st0, st1;
  {
    const u32 byt = (O < 8) ? ((u32)(sb >> (O * 8)) & 0xFFu) : sb8;
#pragma unroll
    for (int e = 0; e < 4; ++e) {
      st0[e] = (_Float16)(float)((byt >> e) & 1u);
      st1[e] = (_Float16)(float)((byt >> (4 + e)) & 1u);
    }
  }
  u64 msgc[9];
#pragma unroll
  for (int i = 0; i < 9; ++i)
    msgc[i] = P ? msg[O][i] : msg[i][O];
  jt_range<P, O, 0, 5, 0>(bufA, msg, msgc, st0, st1, stc, lane);
  asm volatile("s_waitcnt vmcnt(0)" ::: "memory");
  __syncthreads();
  if (step + 1 < 54)
    stage_bytes(ws + (size_t)(step + 1) * STEP_BYTES, bufA, PHA_SZ, tid);
  else
    stage_bytes(ws + WS_LAYER, bufA, CPA_SZ, tid);
  jt_range<P, O, 5, 9, PHA_SZ>(bufB, msg, msgc, st0, st1, stc, lane);
}

__global__ __launch_bounds__(256, 1) void mix_main(
    const float* __restrict__ mask, const float* __restrict__ board,
    const float* __restrict__ common_b, const float* __restrict__ wdl_w,
    const float* __restrict__ wdl_b, const unsigned char* __restrict__ ws,
    float* __restrict__ out, int Bt)
{
  extern __shared__ unsigned char lds[];
  const int tid = threadIdx.x;
  const int lane = tid & 63;
  const int wid = tid >> 6;
  const int s15 = lane & 15, hq = lane >> 4;
  const int b0 = blockIdx.x * 64 + wid * 16;
  unsigned char* bufA = lds;
  unsigned char* bufB = lds + PHA_SZ;

  stage_bytes(ws, bufA, PHA_SZ, tid);

  u64 msg[9][9];
#pragma unroll
  for (int a = 0; a < 9; ++a)
#pragma unroll
    for (int b = 0; b < 9; ++b) msg[a][b] = 0ull;

  u64 sb = 0ull;
  u32 sb8 = 0u;
  {
    const int b = b0 + s15;
#pragma unroll
    for (int o = 0; o < 9; ++o)
#pragma unroll
      for (int e = 0; e < 4; ++e) {
        const u32 bit0 = static_feat(mask, board, b, o,      4 * hq + e) > 0.5f;
        const u32 bit1 = static_feat(mask, board, b, o, 16 + 4 * hq + e) > 0.5f;
        if (o < 8) sb |= ((u64)bit0 << (o * 8 + e)) | ((u64)bit1 << (o * 8 + 4 + e));
        else       sb8 |= (bit0 << e) | (bit1 << (4 + e));
      }
  }
  f16x4 stc;
  {
    const int b = b0 + s15;
#pragma unroll
    for (int e = 0; e < 4; ++e) {
      const int kidx = 32 + 4 * hq + e;
      stc[e] = (_Float16)((kidx == 45) ? 1.f : static_feat(mask, board, b, 0, kidx));
    }
  }

#define DO_POS(P, O) do_step_layer<P, O>(base, ws, bufA, bufB, msg, sb, sb8, stc, lane, tid);
  for (int dp = 0; dp < 3; ++dp) {
    const int base = dp * 18;
    DO_POS(0,0) DO_POS(0,1) DO_POS(0,2) DO_POS(0,3) DO_POS(0,4)
    DO_POS(0,5) DO_POS(0,6) DO_POS(0,7) DO_POS(0,8)
    DO_POS(1,0) DO_POS(1,1) DO_POS(1,2) DO_POS(1,3) DO_POS(1,4)
    DO_POS(1,5) DO_POS(1,6) DO_POS(1,7) DO_POS(1,8)
  }
#undef DO_POS

  float pw[3] = {0.f, 0.f, 0.f};
  for (int mt = 0; mt < 10; ++mt) {
    asm volatile("s_waitcnt vmcnt(0)" ::: "memory");
    __syncthreads();
    stage_bytes(ws + WS_LAYER + (size_t)mt * CMN_STRIDE + CPA_SZ, bufB, CPB_SZ, tid);
    f32x4 a0 = 0.f;
#pragma unroll
    for (int i = 0; i < 5; ++i) {
      const unsigned char* base = bufA + i * 4608;
#pragma unroll
      for (int p = 0; p < 4; ++p) {
        const f16x8 af = *(const f16x8*)(base + p * 1024 + (size_t)lane * 16);
        const f16x4 alo = __builtin_shufflevector(af, af, 0, 1, 2, 3);
        const f16x4 ahi = __builtin_shufflevector(af, af, 4, 5, 6, 7);
        a0 = mfma16(alo, as_f16x4(msg[i][2 * p]),     a0);
        a0 = mfma16(ahi, as_f16x4(msg[i][2 * p + 1]), a0);
      }
      const f16x4 al = *(const f16x4*)(base + 4096 + (size_t)lane * 8);
      a0 = mfma16(al, as_f16x4(msg[i][8]), a0);
    }
    asm volatile("s_waitcnt vmcnt(0)" ::: "memory");
    __syncthreads();
    if (mt + 1 < 10)
      stage_bytes(ws + WS_LAYER + (size_t)(mt + 1) * CMN_STRIDE, bufA, CPA_SZ, tid);
#pragma unroll
    for (int i = 5; i < 9; ++i) {
      const unsigned char* base = bufB + i * 4608 - CPA_SZ;
#pragma unroll
      for (int p = 0; p < 4; ++p) {
        const f16x8 af = *(const f16x8*)(base + p * 1024 + (size_t)lane * 16);
        const f16x4 alo = __builtin_shufflevector(af, af, 0, 1, 2, 3);
        const f16x4 ahi = __builtin_shufflevector(af, af, 4, 5, 6, 7);
        a0 = mfma16(alo, as_f16x4(msg[i][2 * p]),     a0);
        a0 = mfma16(ahi, as_f16x4(msg[i][2 * p + 1]), a0);
      }
      const f16x4 al = *(const f16x4*)(base + 4096 + (size_t)lane * 8);
      a0 = mfma16(al, as_f16x4(msg[i][8]), a0);
    }
#pragma unroll
    for (int r = 0; r < 4; ++r) {
      const int c = mt * 16 + 4 * hq + r;
      const float bias = (c < 145) ? common_b[c] : 0.f;
      const float v0 = a0[r] + bias;
      if (c < 81) {
        out[(size_t)3 * Bt + (size_t)(b0 + s15) * 81 + c] = v0;
      } else if (c < 145) {
        const float h0 = fmaxf(v0, 0.f);
        const int cc = c - 81;
#pragma unroll
        for (int w = 0; w < 3; ++w)
          pw[w] += h0 * wdl_w[cc * 3 + w];
      }
    }
  }
#pragma unroll
  for (int w = 0; w < 3; ++w) {
    float v0 = pw[w];
    v0 += __shfl_xor(v0, 16, 64); v0 += __shfl_xor(v0, 32, 64);
    if (hq == 0)
      out[(size_t)(b0 + s15) * 3 + w] = v0 + wdl_b[w];
  }
}

// ===========================================================================
// SHARED PROLOGUES (r10-proven K16 fragment layouts)
// ===========================================================================

__global__ __launch_bounds__(256) void conv_layer_w(const float* __restrict__ lw,
                                                    const float* __restrict__ lb,
                                                    unsigned char* __restrict__ dst) {
  const int gid = blockIdx.x * 256 + threadIdx.x;
  if (gid >= 54 * 9 * 6 * 64) return;
  const int lane = gid & 63;
  const int t = gid >> 6;
  const int kp = t % 6, t2 = t / 6;
  const int jp = t2 % 9, dop = t2 / 9;
  const int m = lane & 15, hq = lane >> 4;
  unsigned short v[8];
#pragma unroll
  for (int e = 0; e < 8; ++e) {
    const int kc = kp * 2 + (e >> 2);
    const int kidx = kc * 16 + 4 * hq + (e & 3);
    float f = 0.f;
    if (kidx < 45)        f = lw[((size_t)dop * 189 + kidx) * 144 + jp * 16 + m];
    else if (kidx == 45)  f = lb[(size_t)dop * 144 + jp * 16 + m];
    else if (kidx >= 48)  f = lw[((size_t)dop * 189 + (kidx - 3)) * 144 + jp * 16 + m];
    v[e] = f2h(f);
  }
  const u32 w0 = (u32)v[0] | ((u32)v[1] << 16);
  const u32 w1 = (u32)v[2] | ((u32)v[3] << 16);
  const u32 w2 = (u32)v[4] | ((u32)v[5] << 16);
  const u32 w3 = (u32)v[6] | ((u32)v[7] << 16);
  *(uint4*)(dst + (size_t)gid * 16) = make_uint4(w0, w1, w2, w3);
}

__global__ __launch_bounds__(256) void conv_common_w(const float* __restrict__ cw,
                                                     unsigned char* __restrict__ dst) {
  const int gid = blockIdx.x * 256 + threadIdx.x;
  const int NPAIR = 10 * 36 * 64;
  if (gid < NPAIR) {
    const int lane = gid & 63;
    const int t = gid >> 6;
    const int p = t % 4, t2 = t / 4;
    const int i = t2 % 9, mt = t2 / 9;
    const int m = lane & 15, hq = lane >> 4;
    const int c = mt * 16 + m;
    unsigned short v[8];
#pragma unroll
    for (int e = 0; e < 8; ++e) {
      const int ci = i * 9 + 2 * p + (e >> 2);
      const int k = ci * 16 + 4 * hq + (e & 3);
      v[e] = f2h((c < 145) ? cw[(size_t)k * 145 + c] : 0.f);
    }
    const u32 w0 = (u32)v[0] | ((u32)v[1] << 16);
    const u32 w1 = (u32)v[2] | ((u32)v[3] << 16);
    const u32 w2 = (u32)v[4] | ((u32)v[5] << 16);
    const u32 w3 = (u32)v[6] | ((u32)v[7] << 16);
    *(uint4*)(dst + (size_t)WS_LAYER + (size_t)mt * CMN_STRIDE + (size_t)i * 4608
              + (size_t)p * 1024 + (size_t)lane * 16) = make_uint4(w0, w1, w2, w3);
  } else if (gid < NPAIR + 10 * 9 * 64) {
    const int g = gid - NPAIR;
    const int lane = g & 63;
    const int t = g >> 6;
    const int i = t % 9, mt = t / 9;
    const int m = lane & 15, hq = lane >> 4;
    const int c = mt * 16 + m;
    unsigned short v[4];
#pragma unroll
    for (int e = 0; e < 4; ++e) {
      const int k = (i * 9 + 8) * 16 + 4 * hq + e;
      v[e] = f2h((c < 145) ? cw[(size_t)k * 145 + c] : 0.f);
    }
    const u32 w0 = (u32)v[0] | ((u32)v[1] << 16);
    const u32 w1 = (u32)v[2] | ((u32)v[3] << 16);
    *(uint2*)(dst + (size_t)WS_LAYER + (size_t)mt * CMN_STRIDE + (size_t)i * 4608
              + 4096 + (size_t)lane * 8) = make_uint2(w0, w1);
  }
}

// ===========================================================================

extern "C" void kernel_launch(void* const* d_in, const int* in_sizes, int n_in,
                              void* d_out, int out_size, void* d_ws, size_t ws_size,
                              hipStream_t stream) {
  const float* mask     = (const float*)d_in[0];
  const float* board    = (const float*)d_in[1];
  const float* layer_w  = (const float*)d_in[2];
  const float* layer_b  = (const float*)d_in[3];
  const float* common_w = (const float*)d_in[4];
  const float* common_b = (const float*)d_in[5];
  const float* wdl_w    = (const float*)d_in[6];
  const float* wdl_b    = (const float*)d_in[7];
  float* out = (float*)d_out;
  unsigned char* ws = (unsigned char*)d_ws;
  const int Bt = in_sizes[0] / 81;   // 65536

  // ws layout
  const size_t WS_CW_OFF   = (size_t)WS_LAYER;                    // 2,985,984
  const size_t WS_STAT_OFF = WS_CW_OFF + (size_t)10 * CMN_STRIDE; // 3,400,704
  const size_t WS_MSG_OFF  = WS_STAT_OFF + (size_t)19 * Bt * 32;  // +39.8MB
  const size_t WS_WDL_OFF  = WS_MSG_OFF + (size_t)81 * Bt * 32;   // +169.9MB
  const size_t WS_NEED     = WS_WDL_OFF + (size_t)64 * Bt * 4;    // +16.8MB

  hipLaunchKernelGGL(conv_layer_w, dim3((54 * 9 * 6 * 64) / 256), dim3(256), 0, stream,
                     layer_w, layer_b, ws);
  hipLaunchKernelGGL(conv_common_w, dim3((10 * (36 + 9) * 64 + 255) / 256), dim3(256),
                     0, stream, common_w, ws);

  if (ws_size >= WS_NEED) {
    unsigned char* stat = ws + WS_STAT_OFF;
    unsigned char* msgp = ws + WS_MSG_OFF;
    float* wdlbuf = (float*)(ws + WS_WDL_OFF);

    hipLaunchKernelGGL(conv_static, dim3((19 * Bt * 4 + 255) / 256), dim3(256), 0, stream,
                       mask, board, stat, Bt);

    const dim3 lgrid(Bt / 256, 9);
    hipLaunchKernelGGL((layer_step<0, 1>), lgrid, dim3(576), 0, stream, ws, stat, msgp, 0, Bt);
    hipLaunchKernelGGL((layer_step<1, 0>), lgrid, dim3(576), 0, stream, ws, stat, msgp, 1, Bt);
    hipLaunchKernelGGL((layer_step<0, 0>), lgrid, dim3(576), 0, stream, ws, stat, msgp, 2, Bt);
    hipLaunchKernelGGL((layer_step<1, 0>), lgrid, dim3(576), 0, stream, ws, stat, msgp, 3, Bt);
    hipLaunchKernelGGL((layer_step<0, 0>), lgrid, dim3(576), 0, stream, ws, stat, msgp, 4, Bt);
    hipLaunchKernelGGL((layer_step<1, 0>), lgrid, dim3(576), 0, stream, ws, stat, msgp, 5, Bt);

    hipLaunchKernelGGL(common_unf, dim3(Bt / 1024, 10), dim3(256), CMN_STRIDE, stream,
                       ws + WS_CW_OFF, msgp, common_b, wdlbuf, out, Bt);
    hipLaunchKernelGGL(wdl_final, dim3((Bt + 255) / 256), dim3(256), 0, stream,
                       wdlbuf, wdl_w, wdl_b, out, Bt);
  } else {
    (void)hipFuncSetAttribute((const void*)mix_main,
                              hipFuncAttributeMaxDynamicSharedMemorySize, LDS_TOTAL);
    hipLaunchKernelGGL(mix_main, dim3(Bt / 64), dim3(256), LDS_TOTAL, stream,
                       mask, board, common_b, wdl_w, wdl_b, ws, out, Bt);
  }
}

// Round 15
// 533.850 us; speedup vs baseline: 2.9099x; 2.9099x over previous
//
#include <hip/hip_runtime.h>
#include <hip/hip_bf16.h>
#include <stdint.h>

// ---------------------------------------------------------------------------
// MixModel (MI355X / gfx950), round 15: unfused v2 — wave-owns-samples.
//
// r14 lesson: common_unf re-read msg 10x (1.7GB, 428us); layer_step had 32
// barrier points/block from the wave-per-output-tile split. v2:
//  - layer_step: wave owns 16 samples, computes all 9 outputs (reads 12
//    B-chunks once; A-panel 54KB in LDS, staged once/block, ONE barrier).
//    No intra-block race (waves touch disjoint samples). 4 waves/SIMD.
//  - common_unf: block owns 64 samples, acc[10] in regs, loops i staging the
//    45KB i-slice of W (new i-major layout via conv_common_w2); msg read ONCE.
//  - layouts (stat/msg cells, K16 fragment maps) identical to r14 (proven).
//  - fused r10 kernel kept as fallback (uses old mt-major W layout).
// ---------------------------------------------------------------------------

typedef __attribute__((ext_vector_type(4))) float    f32x4;
typedef __attribute__((ext_vector_type(4))) _Float16 f16x4;
typedef __attribute__((ext_vector_type(8))) _Float16 f16x8;
typedef unsigned long long u64;
typedef unsigned int u32;

#define STEP_BYTES 55296            // 9 jt * 6 slices * 64 lanes * 16B
#define PHA_SZ     30720            // fused path: jt 0..4
#define PHB_SZ     24576            // fused path: jt 5..8
#define CMN_STRIDE 41472            // fused path: per-mt panel
#define CSL_SZ     46080            // unfused: per-i slice (10 mt * 4608)
#define CPA_SZ     23040
#define CPB_SZ     18432
#define WS_LAYER   (54*STEP_BYTES)  // 2,985,984
#define LDS_TOTAL  (2*PHA_SZ)       // fused path dynamic LDS

__device__ __forceinline__ unsigned short f2h(float f) {
  return __builtin_bit_cast(unsigned short, (_Float16)f);
}
__device__ __forceinline__ u64 as_u64(f16x4 v) { return __builtin_bit_cast(u64, v); }
__device__ __forceinline__ f16x4 as_f16x4(u64 v) { return __builtin_bit_cast(f16x4, v); }

__device__ __forceinline__ f32x4 mfma16(f16x4 a, f16x4 b, f32x4 c) {
#if __has_builtin(__builtin_amdgcn_mfma_f32_16x16x16f16)
  return __builtin_amdgcn_mfma_f32_16x16x16f16(a, b, c, 0, 0, 0);
#else
  asm("v_mfma_f32_16x16x16_f16 %0, %1, %2, %0" : "+v"(c) : "v"(a), "v"(b));
  return c;
#endif
}

__device__ __forceinline__ float static_feat(const float* __restrict__ mask,
                                             const float* __restrict__ board,
                                             int b, int o, int kidx) {
  if (kidx < 9)  return mask [b*81  + o*9 + kidx];
  if (kidx < 18) return board[b*180 +       o*9 + (kidx - 9)];
  if (kidx < 27) return board[b*180 + 90 +  o*9 + (kidx - 18)];
  if (kidx < 36) return board[b*180 +       81 + (kidx - 27)];
  if (kidx < 45) return board[b*180 + 90 +  81 + (kidx - 36)];
  return 0.f;
}

// async stage nbytes (16B-granular, n16 % 64 == 0) into LDS across NTH threads
template<int NTH>
__device__ __forceinline__ void stage_n(const unsigned char* __restrict__ src,
                                        unsigned char* dstlds, int nbytes, int tid) {
  const int n16 = nbytes / 16;
  const int ubase = tid & ~63;
  for (int k = 0; k * NTH < n16; ++k) {
    const int idx = k * NTH + tid;
    if (idx < n16) {
      __builtin_amdgcn_global_load_lds(
          (const __attribute__((address_space(1))) void*)(src + (size_t)idx * 16),
          (__attribute__((address_space(3))) void*)(dstlds + (size_t)(k * NTH + ubase) * 16),
          16, 0, 0);
    }
  }
}

// ===========================================================================
// UNFUSED PATH v2
// ===========================================================================

// B-chunk loads for one 16-sample tile (coalesced: 512B/chunk/wave)
template<int P, int FIRST>
__device__ __forceinline__ void load_B(u64 (&B)[12],
    const unsigned char* __restrict__ stat, const unsigned char* __restrict__ msg,
    int o, int b0, int s15, int hq, int Bt)
{
  const size_t lo = (size_t)(b0 + s15) * 32 + (size_t)hq * 8;
  B[0] = *(const u64*)(stat + ((size_t)(o * 2 + 0) * Bt) * 32 + lo);
  B[1] = *(const u64*)(stat + ((size_t)(o * 2 + 1) * Bt) * 32 + lo);
  B[2] = *(const u64*)(stat + ((size_t)18 * Bt) * 32 + lo);
  if (!FIRST) {
#pragma unroll
    for (int i = 0; i < 9; ++i) {
      const int cell = P ? (o * 9 + i) : (i * 9 + o);
      B[3 + i] = *(const u64*)(msg + ((size_t)cell * Bt) * 32 + lo);
    }
  }
}

// one layer: grid (Bt/128, 9), 512 thr = 8 waves; wave owns 16 samples and
// computes all 9 output chunks. A-panel (54KB) in LDS, staged once, 1 barrier.
template<int P, int FIRST>
__global__ __launch_bounds__(512, 4) void layer_step(
    const unsigned char* __restrict__ wsLW, const unsigned char* __restrict__ stat,
    unsigned char* __restrict__ msg, int d, int Bt)
{
  __shared__ unsigned char panel[STEP_BYTES];
  const int tid = threadIdx.x;
  const int lane = tid & 63;
  const int wid = tid >> 6;
  const int o = blockIdx.y;
  const int s15 = lane & 15, hq = lane >> 4;

  stage_n<512>(wsLW + (size_t)(d * 9 + o) * STEP_BYTES, panel, STEP_BYTES, tid);

  const int b0 = blockIdx.x * 128 + wid * 16;
  u64 B[12];
  load_B<P, FIRST>(B, stat, msg, o, b0, s15, hq, Bt);

  asm volatile("s_waitcnt vmcnt(0)" ::: "memory");
  __syncthreads();   // panel ready (B loads also drained; harmless)

  const unsigned char* pl = panel + (size_t)lane * 16;
  const size_t lo = (size_t)(b0 + s15) * 32 + (size_t)hq * 8;
#pragma unroll
  for (int j = 0; j < 9; ++j) {
    f32x4 acc = 0.f;
#pragma unroll
    for (int s = 0; s < (FIRST ? 2 : 6); ++s) {
      const f16x8 af = *(const f16x8*)(pl + j * 6144 + s * 1024);
      const f16x4 alo = __builtin_shufflevector(af, af, 0, 1, 2, 3);
      acc = mfma16(alo, as_f16x4(B[2 * s]), acc);
      if (!FIRST || s == 0) {
        const f16x4 ahi = __builtin_shufflevector(af, af, 4, 5, 6, 7);
        acc = mfma16(ahi, as_f16x4(B[2 * s + 1]), acc);
      }
    }
    f16x4 h;
#pragma unroll
    for (int r = 0; r < 4; ++r)
      h[r] = (_Float16)fmaxf(acc[r], 0.f);
    const int wcell = P ? (o * 9 + j) : (j * 9 + o);
    *(u64*)(msg + ((size_t)wcell * Bt) * 32 + lo) = as_u64(h);
  }
}

// common layer: grid (Bt/64), 256 thr = 4 waves; wave owns 16 samples, keeps
// acc[10] (all M-tiles) in regs; loops i staging the 45KB i-slice of W in LDS;
// msg chunks read ONCE per sample.
__global__ __launch_bounds__(256, 4) void common_unf(
    const unsigned char* __restrict__ wsCW, const unsigned char* __restrict__ msg,
    const float* __restrict__ common_b, float* __restrict__ wdlbuf,
    float* __restrict__ out, int Bt)
{
  __shared__ unsigned char sl[CSL_SZ];
  const int tid = threadIdx.x;
  const int lane = tid & 63;
  const int wid = tid >> 6;
  const int s15 = lane & 15, hq = lane >> 4;
  const int b0 = blockIdx.x * 64 + wid * 16;
  const size_t lo = (size_t)(b0 + s15) * 32 + (size_t)hq * 8;

  f32x4 acc[10];
#pragma unroll
  for (int mt = 0; mt < 10; ++mt) acc[mt] = 0.f;

  for (int i = 0; i < 9; ++i) {
    __syncthreads();            // all waves done reading previous slice
    stage_n<256>(wsCW + (size_t)i * CSL_SZ, sl, CSL_SZ, tid);
    asm volatile("s_waitcnt vmcnt(0)" ::: "memory");
    __syncthreads();

    u64 m[9];
#pragma unroll
    for (int jj = 0; jj < 9; ++jj)
      m[jj] = *(const u64*)(msg + ((size_t)(i * 9 + jj) * Bt) * 32 + lo);

#pragma unroll
    for (int mt = 0; mt < 10; ++mt) {
      const unsigned char* base = sl + mt * 4608;
#pragma unroll
      for (int p = 0; p < 4; ++p) {
        const f16x8 a8 = *(const f16x8*)(base + p * 1024 + (size_t)lane * 16);
        const f16x4 alo = __builtin_shufflevector(a8, a8, 0, 1, 2, 3);
        const f16x4 ahi = __builtin_shufflevector(a8, a8, 4, 5, 6, 7);
        acc[mt] = mfma16(alo, as_f16x4(m[2 * p]),     acc[mt]);
        acc[mt] = mfma16(ahi, as_f16x4(m[2 * p + 1]), acc[mt]);
      }
      const f16x4 al = *(const f16x4*)(base + 4096 + (size_t)lane * 8);
      acc[mt] = mfma16(al, as_f16x4(m[8]), acc[mt]);
    }
  }

#pragma unroll
  for (int mt = 0; mt < 10; ++mt) {
#pragma unroll
    for (int r = 0; r < 4; ++r) {
      const int c = mt * 16 + 4 * hq + r;
      if (c < 145) {
        const float v = acc[mt][r] + common_b[c];
        if (c < 81) out[(size_t)3 * Bt + (size_t)(b0 + s15) * 81 + c] = v;
        else        wdlbuf[(size_t)(c - 81) * Bt + (b0 + s15)] = v;  // raw
      }
    }
  }
}

// wdl head: out[b] = relu(hidden) @ wdl_w + wdl_b
__global__ __launch_bounds__(256) void wdl_final(
    const float* __restrict__ wdlbuf, const float* __restrict__ wdl_w,
    const float* __restrict__ wdl_b, float* __restrict__ out, int Bt)
{
  const int b = blockIdx.x * 256 + threadIdx.x;
  if (b >= Bt) return;
  float s0 = wdl_b[0], s1 = wdl_b[1], s2 = wdl_b[2];
  for (int cc = 0; cc < 64; ++cc) {
    const float h = fmaxf(wdlbuf[(size_t)cc * Bt + b], 0.f);
    s0 += h * wdl_w[cc * 3 + 0];
    s1 += h * wdl_w[cc * 3 + 1];
    s2 += h * wdl_w[cc * 3 + 2];
  }
  out[(size_t)b * 3 + 0] = s0;
  out[(size_t)b * 3 + 1] = s1;
  out[(size_t)b * 3 + 2] = s2;
}

// prologue: pack static features -> B-chunk layout (r14-proven)
__global__ __launch_bounds__(256) void conv_static(
    const float* __restrict__ mask, const float* __restrict__ board,
    unsigned char* __restrict__ stat, int Bt)
{
  const int gid = blockIdx.x * 256 + threadIdx.x;   // (slot, b, hq)
  if (gid >= 19 * Bt * 4) return;
  const int hq = gid & 3;
  const int b = (gid >> 2) % Bt;
  const int slot = gid / (Bt * 4);
  const int o = (slot < 18) ? (slot >> 1) : 0;
  const int c = (slot < 18) ? (slot & 1) : 2;
  unsigned short v[4];
#pragma unroll
  for (int e = 0; e < 4; ++e) {
    const int kidx = c * 16 + 4 * hq + e;
    v[e] = f2h((kidx == 45) ? 1.f : static_feat(mask, board, b, o, kidx));
  }
  const u32 w0 = (u32)v[0] | ((u32)v[1] << 16);
  const u32 w1 = (u32)v[2] | ((u32)v[3] << 16);
  *(uint2*)(stat + (size_t)gid * 8) = make_uint2(w0, w1);
}

// prologue: common weights -> i-MAJOR fp16 fragment layout (unfused path)
// dst = i*46080 + mt*4608 + p*1024 + lane*16 (pairs) / + 4096 + lane*8 (left)
__global__ __launch_bounds__(256) void conv_common_w2(const float* __restrict__ cw,
                                                      unsigned char* __restrict__ dst) {
  const int gid = blockIdx.x * 256 + threadIdx.x;
  const int NPAIR = 10 * 36 * 64;
  if (gid < NPAIR) {
    const int lane = gid & 63;
    const int t = gid >> 6;
    const int p = t % 4, t2 = t / 4;
    const int i = t2 % 9, mt = t2 / 9;
    const int m = lane & 15, hq = lane >> 4;
    const int c = mt * 16 + m;
    unsigned short v[8];
#pragma unroll
    for (int e = 0; e < 8; ++e) {
      const int ci = i * 9 + 2 * p + (e >> 2);
      const int k = ci * 16 + 4 * hq + (e & 3);
      v[e] = f2h((c < 145) ? cw[(size_t)k * 145 + c] : 0.f);
    }
    const u32 w0 = (u32)v[0] | ((u32)v[1] << 16);
    const u32 w1 = (u32)v[2] | ((u32)v[3] << 16);
    const u32 w2 = (u32)v[4] | ((u32)v[5] << 16);
    const u32 w3 = (u32)v[6] | ((u32)v[7] << 16);
    *(uint4*)(dst + (size_t)i * CSL_SZ + (size_t)mt * 4608
              + (size_t)p * 1024 + (size_t)lane * 16) = make_uint4(w0, w1, w2, w3);
  } else if (gid < NPAIR + 10 * 9 * 64) {
    const int g = gid - NPAIR;
    const int lane = g & 63;
    const int t = g >> 6;
    const int i = t % 9, mt = t / 9;
    const int m = lane & 15, hq = lane >> 4;
    const int c = mt * 16 + m;
    unsigned short v[4];
#pragma unroll
    for (int e = 0; e < 4; ++e) {
      const int k = (i * 9 + 8) * 16 + 4 * hq + e;
      v[e] = f2h((c < 145) ? cw[(size_t)k * 145 + c] : 0.f);
    }
    const u32 w0 = (u32)v[0] | ((u32)v[1] << 16);
    const u32 w1 = (u32)v[2] | ((u32)v[3] << 16);
    *(uint2*)(dst + (size_t)i * CSL_SZ + (size_t)mt * 4608
              + 4096 + (size_t)lane * 8) = make_uint2(w0, w1);
  }
}

// ===========================================================================
// FUSED FALLBACK (r10, proven 734us) + its mt-major common-W prologue
// ===========================================================================

template<int P, int O, int J0, int J1, int OFF>
__device__ __forceinline__ void jt_range(const unsigned char* __restrict__ buf,
    u64 (&msg)[9][9], const u64 (&msgc)[9], f16x4 st0, f16x4 st1, f16x4 stc, int lane)
{
  const unsigned char* abase = buf + (size_t)lane * 16 - OFF;
#pragma unroll
  for (int j = J0; j < J1; ++j) {
    f32x4 acc = 0.f;
#pragma unroll
    for (int sp = 0; sp < 6; ++sp) {
      const f16x8 af = *(const f16x8*)(abase + j * 6144 + sp * 1024);
      const f16x4 alo = __builtin_shufflevector(af, af, 0, 1, 2, 3);
      const f16x4 ahi = __builtin_shufflevector(af, af, 4, 5, 6, 7);
      const int c0 = 2 * sp, c1 = 2 * sp + 1;
      if (c0 == 0)      acc = mfma16(alo, st0, acc);
      else if (c0 == 2) acc = mfma16(alo, stc, acc);
      else              acc = mfma16(alo, as_f16x4(msgc[c0 - 3]), acc);
      if (c1 == 1)      acc = mfma16(ahi, st1, acc);
      else              acc = mfma16(ahi, as_f16x4(msgc[c1 - 3]), acc);
    }
    f16x4 h;
#pragma unroll
    for (int r = 0; r < 4; ++r)
      h[r] = (_Float16)fmaxf(acc[r], 0.f);
    if (P) msg[O][j] = as_u64(h); else msg[j][O] = as_u64(h);
  }
}

template<int P, int O>
__device__ __forceinline__ void do_step_layer(int base, const unsigned char* __restrict__ ws,
    unsigned char* bufA, unsigned char* bufB, u64 (&msg)[9][9],
    u64 sb, u32 sb8, f16x4 stc, int lane, int tid)
{
  const int step = base + P * 9 + O;
  asm volatile("s_waitcnt vmcnt(0)" ::: "memory");
  __syncthreads();
  stage_n<256>(ws + (size_t)step * STEP_BYTES + PHA_SZ, bufB, PHB_SZ, tid);
  f16x4 st0, st1;
  {
    const u32 byt = (O < 8) ? ((u32)(sb >> (O * 8)) & 0xFFu) : sb8;
#pragma unroll
    for (int e = 0; e < 4; ++e) {
      st0[e] = (_Float16)(float)((byt >> e) & 1u);
      st1[e] = (_Float16)(float)((byt >> (4 + e)) & 1u);
    }
  }
  u64 msgc[9];
#pragma unroll
  for (int i = 0; i < 9; ++i)
    msgc[i] = P ? msg[O][i] : msg[i][O];
  jt_range<P, O, 0, 5, 0>(bufA, msg, msgc, st0, st1, stc, lane);
  asm volatile("s_waitcnt vmcnt(0)" ::: "memory");
  __syncthreads();
  if (step + 1 < 54)
    stage_n<256>(ws + (size_t)(step + 1) * STEP_BYTES, bufA, PHA_SZ, tid);
  else
    stage_n<256>(ws + WS_LAYER, bufA, CPA_SZ, tid);
  jt_range<P, O, 5, 9, PHA_SZ>(bufB, msg, msgc, st0, st1, stc, lane);
}

__global__ __launch_bounds__(256, 1) void mix_main(
    const float* __restrict__ mask, const float* __restrict__ board,
    const float* __restrict__ common_b, const float* __restrict__ wdl_w,
    const float* __restrict__ wdl_b, const unsigned char* __restrict__ ws,
    float* __restrict__ out, int Bt)
{
  extern __shared__ unsigned char lds[];
  const int tid = threadIdx.x;
  const int lane = tid & 63;
  const int wid = tid >> 6;
  const int s15 = lane & 15, hq = lane >> 4;
  const int b0 = blockIdx.x * 64 + wid * 16;
  unsigned char* bufA = lds;
  unsigned char* bufB = lds + PHA_SZ;

  stage_n<256>(ws, bufA, PHA_SZ, tid);

  u64 msg[9][9];
#pragma unroll
  for (int a = 0; a < 9; ++a)
#pragma unroll
    for (int b = 0; b < 9; ++b) msg[a][b] = 0ull;

  u64 sb = 0ull;
  u32 sb8 = 0u;
  {
    const int b = b0 + s15;
#pragma unroll
    for (int o = 0; o < 9; ++o)
#pragma unroll
      for (int e = 0; e < 4; ++e) {
        const u32 bit0 = static_feat(mask, board, b, o,      4 * hq + e) > 0.5f;
        const u32 bit1 = static_feat(mask, board, b, o, 16 + 4 * hq + e) > 0.5f;
        if (o < 8) sb |= ((u64)bit0 << (o * 8 + e)) | ((u64)bit1 << (o * 8 + 4 + e));
        else       sb8 |= (bit0 << e) | (bit1 << (4 + e));
      }
  }
  f16x4 stc;
  {
    const int b = b0 + s15;
#pragma unroll
    for (int e = 0; e < 4; ++e) {
      const int kidx = 32 + 4 * hq + e;
      stc[e] = (_Float16)((kidx == 45) ? 1.f : static_feat(mask, board, b, 0, kidx));
    }
  }

#define DO_POS(P, O) do_step_layer<P, O>(base, ws, bufA, bufB, msg, sb, sb8, stc, lane, tid);
  for (int dp = 0; dp < 3; ++dp) {
    const int base = dp * 18;
    DO_POS(0,0) DO_POS(0,1) DO_POS(0,2) DO_POS(0,3) DO_POS(0,4)
    DO_POS(0,5) DO_POS(0,6) DO_POS(0,7) DO_POS(0,8)
    DO_POS(1,0) DO_POS(1,1) DO_POS(1,2) DO_POS(1,3) DO_POS(1,4)
    DO_POS(1,5) DO_POS(1,6) DO_POS(1,7) DO_POS(1,8)
  }
#undef DO_POS

  float pw[3] = {0.f, 0.f, 0.f};
  for (int mt = 0; mt < 10; ++mt) {
    asm volatile("s_waitcnt vmcnt(0)" ::: "memory");
    __syncthreads();
    stage_n<256>(ws + WS_LAYER + (size_t)mt * CMN_STRIDE + CPA_SZ, bufB, CPB_SZ, tid);
    f32x4 a0 = 0.f;
#pragma unroll
    for (int i = 0; i < 5; ++i) {
      const unsigned char* base = bufA + i * 4608;
#pragma unroll
      for (int p = 0; p < 4; ++p) {
        const f16x8 af = *(const f16x8*)(base + p * 1024 + (size_t)lane * 16);
        const f16x4 alo = __builtin_shufflevector(af, af, 0, 1, 2, 3);
        const f16x4 ahi = __builtin_shufflevector(af, af, 4, 5, 6, 7);
        a0 = mfma16(alo, as_f16x4(msg[i][2 * p]),     a0);
        a0 = mfma16(ahi, as_f16x4(msg[i][2 * p + 1]), a0);
      }
      const f16x4 al = *(const f16x4*)(base + 4096 + (size_t)lane * 8);
      a0 = mfma16(al, as_f16x4(msg[i][8]), a0);
    }
    asm volatile("s_waitcnt vmcnt(0)" ::: "memory");
    __syncthreads();
    if (mt + 1 < 10)
      stage_n<256>(ws + WS_LAYER + (size_t)(mt + 1) * CMN_STRIDE, bufA, CPA_SZ, tid);
#pragma unroll
    for (int i = 5; i < 9; ++i) {
      const unsigned char* base = bufB + i * 4608 - CPA_SZ;
#pragma unroll
      for (int p = 0; p < 4; ++p) {
        const f16x8 af = *(const f16x8*)(base + p * 1024 + (size_t)lane * 16);
        const f16x4 alo = __builtin_shufflevector(af, af, 0, 1, 2, 3);
        const f16x4 ahi = __builtin_shufflevector(af, af, 4, 5, 6, 7);
        a0 = mfma16(alo, as_f16x4(msg[i][2 * p]),     a0);
        a0 = mfma16(ahi, as_f16x4(msg[i][2 * p + 1]), a0);
      }
      const f16x4 al = *(const f16x4*)(base + 4096 + (size_t)lane * 8);
      a0 = mfma16(al, as_f16x4(msg[i][8]), a0);
    }
#pragma unroll
    for (int r = 0; r < 4; ++r) {
      const int c = mt * 16 + 4 * hq + r;
      const float bias = (c < 145) ? common_b[c] : 0.f;
      const float v0 = a0[r] + bias;
      if (c < 81) {
        out[(size_t)3 * Bt + (size_t)(b0 + s15) * 81 + c] = v0;
      } else if (c < 145) {
        const float h0 = fmaxf(v0, 0.f);
        const int cc = c - 81;
#pragma unroll
        for (int w = 0; w < 3; ++w)
          pw[w] += h0 * wdl_w[cc * 3 + w];
      }
    }
  }
#pragma unroll
  for (int w = 0; w < 3; ++w) {
    float v0 = pw[w];
    v0 += __shfl_xor(v0, 16, 64); v0 += __shfl_xor(v0, 32, 64);
    if (hq == 0)
      out[(size_t)(b0 + s15) * 3 + w] = v0 + wdl_b[w];
  }
}

// ===========================================================================
// SHARED / FUSED PROLOGUES (r10-proven layouts)
// ===========================================================================

__global__ __launch_bounds__(256) void conv_layer_w(const float* __restrict__ lw,
                                                    const float* __restrict__ lb,
                                                    unsigned char* __restrict__ dst) {
  const int gid = blockIdx.x * 256 + threadIdx.x;
  if (gid >= 54 * 9 * 6 * 64) return;
  const int lane = gid & 63;
  const int t = gid >> 6;
  const int kp = t % 6, t2 = t / 6;
  const int jp = t2 % 9, dop = t2 / 9;
  const int m = lane & 15, hq = lane >> 4;
  unsigned short v[8];
#pragma unroll
  for (int e = 0; e < 8; ++e) {
    const int kc = kp * 2 + (e >> 2);
    const int kidx = kc * 16 + 4 * hq + (e & 3);
    float f = 0.f;
    if (kidx < 45)        f = lw[((size_t)dop * 189 + kidx) * 144 + jp * 16 + m];
    else if (kidx == 45)  f = lb[(size_t)dop * 144 + jp * 16 + m];
    else if (kidx >= 48)  f = lw[((size_t)dop * 189 + (kidx - 3)) * 144 + jp * 16 + m];
    v[e] = f2h(f);
  }
  const u32 w0 = (u32)v[0] | ((u32)v[1] << 16);
  const u32 w1 = (u32)v[2] | ((u32)v[3] << 16);
  const u32 w2 = (u32)v[4] | ((u32)v[5] << 16);
  const u32 w3 = (u32)v[6] | ((u32)v[7] << 16);
  *(uint4*)(dst + (size_t)gid * 16) = make_uint4(w0, w1, w2, w3);
}

__global__ __launch_bounds__(256) void conv_common_w(const float* __restrict__ cw,
                                                     unsigned char* __restrict__ dst) {
  const int gid = blockIdx.x * 256 + threadIdx.x;
  const int NPAIR = 10 * 36 * 64;
  if (gid < NPAIR) {
    const int lane = gid & 63;
    const int t = gid >> 6;
    const int p = t % 4, t2 = t / 4;
    const int i = t2 % 9, mt = t2 / 9;
    const int m = lane & 15, hq = lane >> 4;
    const int c = mt * 16 + m;
    unsigned short v[8];
#pragma unroll
    for (int e = 0; e < 8; ++e) {
      const int ci = i * 9 + 2 * p + (e >> 2);
      const int k = ci * 16 + 4 * hq + (e & 3);
      v[e] = f2h((c < 145) ? cw[(size_t)k * 145 + c] : 0.f);
    }
    const u32 w0 = (u32)v[0] | ((u32)v[1] << 16);
    const u32 w1 = (u32)v[2] | ((u32)v[3] << 16);
    const u32 w2 = (u32)v[4] | ((u32)v[5] << 16);
    const u32 w3 = (u32)v[6] | ((u32)v[7] << 16);
    *(uint4*)(dst + (size_t)WS_LAYER + (size_t)mt * CMN_STRIDE + (size_t)i * 4608
              + (size_t)p * 1024 + (size_t)lane * 16) = make_uint4(w0, w1, w2, w3);
  } else if (gid < NPAIR + 10 * 9 * 64) {
    const int g = gid - NPAIR;
    const int lane = g & 63;
    const int t = g >> 6;
    const int i = t % 9, mt = t / 9;
    const int m = lane & 15, hq = lane >> 4;
    const int c = mt * 16 + m;
    unsigned short v[4];
#pragma unroll
    for (int e = 0; e < 4; ++e) {
      const int k = (i * 9 + 8) * 16 + 4 * hq + e;
      v[e] = f2h((c < 145) ? cw[(size_t)k * 145 + c] : 0.f);
    }
    const u32 w0 = (u32)v[0] | ((u32)v[1] << 16);
    const u32 w1 = (u32)v[2] | ((u32)v[3] << 16);
    *(uint2*)(dst + (size_t)WS_LAYER + (size_t)mt * CMN_STRIDE + (size_t)i * 4608
              + 4096 + (size_t)lane * 8) = make_uint2(w0, w1);
  }
}

// ===========================================================================

extern "C" void kernel_launch(void* const* d_in, const int* in_sizes, int n_in,
                              void* d_out, int out_size, void* d_ws, size_t ws_size,
                              hipStream_t stream) {
  const float* mask     = (const float*)d_in[0];
  const float* board    = (const float*)d_in[1];
  const float* layer_w  = (const float*)d_in[2];
  const float* layer_b  = (const float*)d_in[3];
  const float* common_w = (const float*)d_in[4];
  const float* common_b = (const float*)d_in[5];
  const float* wdl_w    = (const float*)d_in[6];
  const float* wdl_b    = (const float*)d_in[7];
  float* out = (float*)d_out;
  unsigned char* ws = (unsigned char*)d_ws;
  const int Bt = in_sizes[0] / 81;   // 65536

  // ws layout (CW region shared by both paths at WS_LAYER, layouts differ)
  const size_t WS_CW_OFF   = (size_t)WS_LAYER;                    // 2,985,984
  const size_t WS_STAT_OFF = WS_CW_OFF + (size_t)9 * CSL_SZ;      // 3,400,704
  const size_t WS_MSG_OFF  = WS_STAT_OFF + (size_t)19 * Bt * 32;
  const size_t WS_WDL_OFF  = WS_MSG_OFF + (size_t)81 * Bt * 32;
  const size_t WS_NEED     = WS_WDL_OFF + (size_t)64 * Bt * 4;

  hipLaunchKernelGGL(conv_layer_w, dim3((54 * 9 * 6 * 64) / 256), dim3(256), 0, stream,
                     layer_w, layer_b, ws);

  if (ws_size >= WS_NEED) {
    unsigned char* stat = ws + WS_STAT_OFF;
    unsigned char* msgp = ws + WS_MSG_OFF;
    float* wdlbuf = (float*)(ws + WS_WDL_OFF);

    hipLaunchKernelGGL(conv_common_w2, dim3((10 * (36 + 9) * 64 + 255) / 256), dim3(256),
                       0, stream, common_w, ws + WS_CW_OFF);
    hipLaunchKernelGGL(conv_static, dim3((19 * Bt * 4 + 255) / 256), dim3(256), 0, stream,
                       mask, board, stat, Bt);

    const dim3 lgrid(Bt / 128, 9);
    hipLaunchKernelGGL((layer_step<0, 1>), lgrid, dim3(512), 0, stream, ws, stat, msgp, 0, Bt);
    hipLaunchKernelGGL((layer_step<1, 0>), lgrid, dim3(512), 0, stream, ws, stat, msgp, 1, Bt);
    hipLaunchKernelGGL((layer_step<0, 0>), lgrid, dim3(512), 0, stream, ws, stat, msgp, 2, Bt);
    hipLaunchKernelGGL((layer_step<1, 0>), lgrid, dim3(512), 0, stream, ws, stat, msgp, 3, Bt);
    hipLaunchKernelGGL((layer_step<0, 0>), lgrid, dim3(512), 0, stream, ws, stat, msgp, 4, Bt);
    hipLaunchKernelGGL((layer_step<1, 0>), lgrid, dim3(512), 0, stream, ws, stat, msgp, 5, Bt);

    hipLaunchKernelGGL(common_unf, dim3(Bt / 64), dim3(256), 0, stream,
                       ws + WS_CW_OFF, msgp, common_b, wdlbuf, out, Bt);
    hipLaunchKernelGGL(wdl_final, dim3((Bt + 255) / 256), dim3(256), 0, stream,
                       wdlbuf, wdl_w, wdl_b, out, Bt);
  } else {
    hipLaunchKernelGGL(conv_common_w, dim3((10 * (36 + 9) * 64 + 255) / 256), dim3(256),
                       0, stream, common_w, ws);
    (void)hipFuncSetAttribute((const void*)mix_main,
                              hipFuncAttributeMaxDynamicSharedMemorySize, LDS_TOTAL);
    hipLaunchKernelGGL(mix_main, dim3(Bt / 64), dim3(256), LDS_TOTAL, stream,
                       mask, board, common_b, wdl_w, wdl_b, ws, out, Bt);
  }
}

// Round 16
// 451.681 us; speedup vs baseline: 3.4392x; 1.1819x over previous
//
#include <hip/hip_runtime.h>
#include <hip/hip_bf16.h>
#include <stdint.h>

// ---------------------------------------------------------------------------
// MixModel (MI355X / gfx950), round 16: unfused v3 — LDS-BW + reshape fixes.
//
// r15 (533us) breakdown: conv_static 88us (uncoalesced), layer_step ~50us
// each (LDS-BW-bound: every wave re-reads the whole 54KB panel), common ~LDS
// bound too. v3:
//  - layer_step: wave owns 32 samples (2 tiles, B in 48 VGPRs), halving LDS
//    panel traffic; ~90 VGPR -> (512,4) = 4 waves/SIMD.
//  - common_unf: wave owns 32 samples; wdl head fused (r10-proven shfl
//    reduce); no wdlbuf/wdl_final.
//  - conv_static: 16 samples/block staged to LDS via coalesced float4 loads;
//    packed writes 512B/wave.
//  - layouts (stat/msg cells, K16 fragment maps) identical to r15 (proven).
//  - fused r10 kernel kept as fallback.
// ---------------------------------------------------------------------------

typedef __attribute__((ext_vector_type(4))) float    f32x4;
typedef __attribute__((ext_vector_type(4))) _Float16 f16x4;
typedef __attribute__((ext_vector_type(8))) _Float16 f16x8;
typedef unsigned long long u64;
typedef unsigned int u32;

#define STEP_BYTES 55296            // 9 jt * 6 slices * 64 lanes * 16B
#define PHA_SZ     30720            // fused path: jt 0..4
#define PHB_SZ     24576            // fused path: jt 5..8
#define CMN_STRIDE 41472            // fused path: per-mt panel
#define CSL_SZ     46080            // unfused: per-i slice (10 mt * 4608)
#define CPA_SZ     23040
#define CPB_SZ     18432
#define WS_LAYER   (54*STEP_BYTES)  // 2,985,984
#define LDS_TOTAL  (2*PHA_SZ)       // fused path dynamic LDS

__device__ __forceinline__ unsigned short f2h(float f) {
  return __builtin_bit_cast(unsigned short, (_Float16)f);
}
__device__ __forceinline__ u64 as_u64(f16x4 v) { return __builtin_bit_cast(u64, v); }
__device__ __forceinline__ f16x4 as_f16x4(u64 v) { return __builtin_bit_cast(f16x4, v); }

__device__ __forceinline__ f32x4 mfma16(f16x4 a, f16x4 b, f32x4 c) {
#if __has_builtin(__builtin_amdgcn_mfma_f32_16x16x16f16)
  return __builtin_amdgcn_mfma_f32_16x16x16f16(a, b, c, 0, 0, 0);
#else
  asm("v_mfma_f32_16x16x16_f16 %0, %1, %2, %0" : "+v"(c) : "v"(a), "v"(b));
  return c;
#endif
}

__device__ __forceinline__ float static_feat(const float* __restrict__ mask,
                                             const float* __restrict__ board,
                                             int b, int o, int kidx) {
  if (kidx < 9)  return mask [b*81  + o*9 + kidx];
  if (kidx < 18) return board[b*180 +       o*9 + (kidx - 9)];
  if (kidx < 27) return board[b*180 + 90 +  o*9 + (kidx - 18)];
  if (kidx < 36) return board[b*180 +       81 + (kidx - 27)];
  if (kidx < 45) return board[b*180 + 90 +  81 + (kidx - 36)];
  return 0.f;
}

// async stage nbytes (16B-granular, n16 % 64 == 0) into LDS across NTH threads
template<int NTH>
__device__ __forceinline__ void stage_n(const unsigned char* __restrict__ src,
                                        unsigned char* dstlds, int nbytes, int tid) {
  const int n16 = nbytes / 16;
  const int ubase = tid & ~63;
  for (int k = 0; k * NTH < n16; ++k) {
    const int idx = k * NTH + tid;
    if (idx < n16) {
      __builtin_amdgcn_global_load_lds(
          (const __attribute__((address_space(1))) void*)(src + (size_t)idx * 16),
          (__attribute__((address_space(3))) void*)(dstlds + (size_t)(k * NTH + ubase) * 16),
          16, 0, 0);
    }
  }
}

// ===========================================================================
// UNFUSED PATH v3
// ===========================================================================

// B-chunk loads for one 16-sample tile (coalesced: 512B/chunk/wave)
template<int P, int FIRST>
__device__ __forceinline__ void load_B(u64 (&B)[12],
    const unsigned char* __restrict__ stat, const unsigned char* __restrict__ msg,
    int o, int b0, int s15, int hq, int Bt)
{
  const size_t lo = (size_t)(b0 + s15) * 32 + (size_t)hq * 8;
  B[0] = *(const u64*)(stat + ((size_t)(o * 2 + 0) * Bt) * 32 + lo);
  B[1] = *(const u64*)(stat + ((size_t)(o * 2 + 1) * Bt) * 32 + lo);
  B[2] = *(const u64*)(stat + ((size_t)18 * Bt) * 32 + lo);
  if (!FIRST) {
#pragma unroll
    for (int i = 0; i < 9; ++i) {
      const int cell = P ? (o * 9 + i) : (i * 9 + o);
      B[3 + i] = *(const u64*)(msg + ((size_t)cell * Bt) * 32 + lo);
    }
  }
}

// one layer: grid (Bt/256, 9), 512 thr = 8 waves; wave owns 32 samples
// (2 tiles, B in regs), computes all 9 outputs. A-panel in LDS, 1 barrier.
template<int P, int FIRST>
__global__ __launch_bounds__(512, 4) void layer_step(
    const unsigned char* __restrict__ wsLW, const unsigned char* __restrict__ stat,
    unsigned char* __restrict__ msg, int d, int Bt)
{
  __shared__ unsigned char panel[STEP_BYTES];
  const int tid = threadIdx.x;
  const int lane = tid & 63;
  const int wid = tid >> 6;
  const int o = blockIdx.y;
  const int s15 = lane & 15, hq = lane >> 4;

  stage_n<512>(wsLW + (size_t)(d * 9 + o) * STEP_BYTES, panel, STEP_BYTES, tid);

  const int b0 = blockIdx.x * 256 + wid * 32;
  u64 B0[12], B1[12];
  load_B<P, FIRST>(B0, stat, msg, o, b0,      s15, hq, Bt);
  load_B<P, FIRST>(B1, stat, msg, o, b0 + 16, s15, hq, Bt);

  asm volatile("s_waitcnt vmcnt(0)" ::: "memory");
  __syncthreads();   // panel + B ready

  const unsigned char* pl = panel + (size_t)lane * 16;
  const size_t lo0 = (size_t)(b0 + s15) * 32 + (size_t)hq * 8;
  const size_t lo1 = lo0 + 16 * 32;
#pragma unroll
  for (int j = 0; j < 9; ++j) {
    f32x4 a0 = 0.f, a1 = 0.f;
#pragma unroll
    for (int s = 0; s < (FIRST ? 2 : 6); ++s) {
      const f16x8 af = *(const f16x8*)(pl + j * 6144 + s * 1024);
      const f16x4 alo = __builtin_shufflevector(af, af, 0, 1, 2, 3);
      a0 = mfma16(alo, as_f16x4(B0[2 * s]), a0);
      a1 = mfma16(alo, as_f16x4(B1[2 * s]), a1);
      if (!FIRST || s == 0) {
        const f16x4 ahi = __builtin_shufflevector(af, af, 4, 5, 6, 7);
        a0 = mfma16(ahi, as_f16x4(B0[2 * s + 1]), a0);
        a1 = mfma16(ahi, as_f16x4(B1[2 * s + 1]), a1);
      }
    }
    f16x4 h0, h1;
#pragma unroll
    for (int r = 0; r < 4; ++r) {
      h0[r] = (_Float16)fmaxf(a0[r], 0.f);
      h1[r] = (_Float16)fmaxf(a1[r], 0.f);
    }
    const int wcell = P ? (o * 9 + j) : (j * 9 + o);
    unsigned char* wp = msg + ((size_t)wcell * Bt) * 32;
    *(u64*)(wp + lo0) = as_u64(h0);
    *(u64*)(wp + lo1) = as_u64(h1);
  }
}

// common layer: grid (Bt/128), 256 thr = 4 waves; wave owns 32 samples;
// acc[2][10] in regs; loops i staging the 45KB i-slice; msg read ONCE;
// wdl head fused via shfl reduce (r10-proven).
__global__ __launch_bounds__(256, 3) void common_unf(
    const unsigned char* __restrict__ wsCW, const unsigned char* __restrict__ msg,
    const float* __restrict__ common_b, const float* __restrict__ wdl_w,
    const float* __restrict__ wdl_b, float* __restrict__ out, int Bt)
{
  __shared__ unsigned char sl[CSL_SZ];
  const int tid = threadIdx.x;
  const int lane = tid & 63;
  const int wid = tid >> 6;
  const int s15 = lane & 15, hq = lane >> 4;
  const int b0 = blockIdx.x * 128 + wid * 32;
  const size_t lo0 = (size_t)(b0 + s15) * 32 + (size_t)hq * 8;
  const size_t lo1 = lo0 + 16 * 32;

  f32x4 acc0[10], acc1[10];
#pragma unroll
  for (int mt = 0; mt < 10; ++mt) { acc0[mt] = 0.f; acc1[mt] = 0.f; }

  for (int i = 0; i < 9; ++i) {
    __syncthreads();            // all waves done reading previous slice
    stage_n<256>(wsCW + (size_t)i * CSL_SZ, sl, CSL_SZ, tid);

    u64 m0[9], m1[9];
#pragma unroll
    for (int jj = 0; jj < 9; ++jj) {
      const unsigned char* mp = msg + ((size_t)(i * 9 + jj) * Bt) * 32;
      m0[jj] = *(const u64*)(mp + lo0);
      m1[jj] = *(const u64*)(mp + lo1);
    }
    asm volatile("s_waitcnt vmcnt(0)" ::: "memory");
    __syncthreads();

#pragma unroll
    for (int mt = 0; mt < 10; ++mt) {
      const unsigned char* base = sl + mt * 4608;
#pragma unroll
      for (int p = 0; p < 4; ++p) {
        const f16x8 a8 = *(const f16x8*)(base + p * 1024 + (size_t)lane * 16);
        const f16x4 alo = __builtin_shufflevector(a8, a8, 0, 1, 2, 3);
        const f16x4 ahi = __builtin_shufflevector(a8, a8, 4, 5, 6, 7);
        acc0[mt] = mfma16(alo, as_f16x4(m0[2 * p]),     acc0[mt]);
        acc1[mt] = mfma16(alo, as_f16x4(m1[2 * p]),     acc1[mt]);
        acc0[mt] = mfma16(ahi, as_f16x4(m0[2 * p + 1]), acc0[mt]);
        acc1[mt] = mfma16(ahi, as_f16x4(m1[2 * p + 1]), acc1[mt]);
      }
      const f16x4 al = *(const f16x4*)(base + 4096 + (size_t)lane * 8);
      acc0[mt] = mfma16(al, as_f16x4(m0[8]), acc0[mt]);
      acc1[mt] = mfma16(al, as_f16x4(m1[8]), acc1[mt]);
    }
  }

  float pw0[3] = {0.f, 0.f, 0.f}, pw1[3] = {0.f, 0.f, 0.f};
#pragma unroll
  for (int mt = 0; mt < 10; ++mt) {
#pragma unroll
    for (int r = 0; r < 4; ++r) {
      const int c = mt * 16 + 4 * hq + r;
      if (c < 81) {   // policy (no relu)
        out[(size_t)3 * Bt + (size_t)(b0 + s15) * 81 + c]      = acc0[mt][r] + common_b[c];
        out[(size_t)3 * Bt + (size_t)(b0 + 16 + s15) * 81 + c] = acc1[mt][r] + common_b[c];
      } else if (c < 145) {
        const float h0 = fmaxf(acc0[mt][r] + common_b[c], 0.f);
        const float h1 = fmaxf(acc1[mt][r] + common_b[c], 0.f);
        const int cc = c - 81;
#pragma unroll
        for (int w = 0; w < 3; ++w) {
          const float wv = wdl_w[cc * 3 + w];
          pw0[w] += h0 * wv;
          pw1[w] += h1 * wv;
        }
      }
    }
  }
#pragma unroll
  for (int w = 0; w < 3; ++w) {
    float v0 = pw0[w], v1 = pw1[w];
    v0 += __shfl_xor(v0, 16, 64); v0 += __shfl_xor(v0, 32, 64);
    v1 += __shfl_xor(v1, 16, 64); v1 += __shfl_xor(v1, 32, 64);
    if (hq == 0) {
      const float bb = wdl_b[w];
      out[(size_t)(b0 + s15) * 3 + w]      = v0 + bb;
      out[(size_t)(b0 + 16 + s15) * 3 + w] = v1 + bb;
    }
  }
}

// prologue: pack static features -> B-chunk layout (coalesced via LDS)
// 16 samples/block; writes 512B/wave contiguous. Layout identical to r15.
__global__ __launch_bounds__(256) void conv_static(
    const float* __restrict__ mask, const float* __restrict__ board,
    unsigned char* __restrict__ stat, int Bt)
{
  __shared__ float sm[16 * 81];
  __shared__ float sb[16 * 180];
  const int tid = threadIdx.x;
  const int base_b = blockIdx.x * 16;

  const float4* gm = (const float4*)(mask + (size_t)base_b * 81);
  for (int idx = tid; idx < 324; idx += 256) ((float4*)sm)[idx] = gm[idx];
  const float4* gb = (const float4*)(board + (size_t)base_b * 180);
  for (int idx = tid; idx < 720; idx += 256) ((float4*)sb)[idx] = gb[idx];
  __syncthreads();

  const int lane = tid & 63, wv = tid >> 6;
  const int s15 = lane & 15, hq = lane >> 4;
  const float* lm = sm + s15 * 81;
  const float* lb = sb + s15 * 180;
  for (int slot = wv; slot < 19; slot += 4) {
    const int o = (slot < 18) ? (slot >> 1) : 0;
    const int c = (slot < 18) ? (slot & 1) : 2;
    unsigned short v[4];
#pragma unroll
    for (int e = 0; e < 4; ++e) {
      const int kidx = c * 16 + 4 * hq + e;
      float f;
      if (kidx < 9)        f = lm[o * 9 + kidx];
      else if (kidx < 18)  f = lb[o * 9 + (kidx - 9)];
      else if (kidx < 27)  f = lb[90 + o * 9 + (kidx - 18)];
      else if (kidx < 36)  f = lb[81 + (kidx - 27)];
      else if (kidx < 45)  f = lb[90 + 81 + (kidx - 36)];
      else                 f = (kidx == 45) ? 1.f : 0.f;
      v[e] = f2h(f);
    }
    const u32 w0 = (u32)v[0] | ((u32)v[1] << 16);
    const u32 w1 = (u32)v[2] | ((u32)v[3] << 16);
    *(uint2*)(stat + ((size_t)slot * Bt + base_b + s15) * 32 + (size_t)hq * 8)
        = make_uint2(w0, w1);
  }
}

// prologue: common weights -> i-MAJOR fp16 fragment layout (unfused path)
__global__ __launch_bounds__(256) void conv_common_w2(const float* __restrict__ cw,
                                                      unsigned char* __restrict__ dst) {
  const int gid = blockIdx.x * 256 + threadIdx.x;
  const int NPAIR = 10 * 36 * 64;
  if (gid < NPAIR) {
    const int lane = gid & 63;
    const int t = gid >> 6;
    const int p = t % 4, t2 = t / 4;
    const int i = t2 % 9, mt = t2 / 9;
    const int m = lane & 15, hq = lane >> 4;
    const int c = mt * 16 + m;
    unsigned short v[8];
#pragma unroll
    for (int e = 0; e < 8; ++e) {
      const int ci = i * 9 + 2 * p + (e >> 2);
      const int k = ci * 16 + 4 * hq + (e & 3);
      v[e] = f2h((c < 145) ? cw[(size_t)k * 145 + c] : 0.f);
    }
    const u32 w0 = (u32)v[0] | ((u32)v[1] << 16);
    const u32 w1 = (u32)v[2] | ((u32)v[3] << 16);
    const u32 w2 = (u32)v[4] | ((u32)v[5] << 16);
    const u32 w3 = (u32)v[6] | ((u32)v[7] << 16);
    *(uint4*)(dst + (size_t)i * CSL_SZ + (size_t)mt * 4608
              + (size_t)p * 1024 + (size_t)lane * 16) = make_uint4(w0, w1, w2, w3);
  } else if (gid < NPAIR + 10 * 9 * 64) {
    const int g = gid - NPAIR;
    const int lane = g & 63;
    const int t = g >> 6;
    const int i = t % 9, mt = t / 9;
    const int m = lane & 15, hq = lane >> 4;
    const int c = mt * 16 + m;
    unsigned short v[4];
#pragma unroll
    for (int e = 0; e < 4; ++e) {
      const int k = (i * 9 + 8) * 16 + 4 * hq + e;
      v[e] = f2h((c < 145) ? cw[(size_t)k * 145 + c] : 0.f);
    }
    const u32 w0 = (u32)v[0] | ((u32)v[1] << 16);
    const u32 w1 = (u32)v[2] | ((u32)v[3] << 16);
    *(uint2*)(dst + (size_t)i * CSL_SZ + (size_t)mt * 4608
              + 4096 + (size_t)lane * 8) = make_uint2(w0, w1);
  }
}

// ===========================================================================
// FUSED FALLBACK (r10, proven 734us) + its mt-major common-W prologue
// ===========================================================================

template<int P, int O, int J0, int J1, int OFF>
__device__ __forceinline__ void jt_range(const unsigned char* __restrict__ buf,
    u64 (&msg)[9][9], const u64 (&msgc)[9], f16x4 st0, f16x4 st1, f16x4 stc, int lane)
{
  const unsigned char* abase = buf + (size_t)lane * 16 - OFF;
#pragma unroll
  for (int j = J0; j < J1; ++j) {
    f32x4 acc = 0.f;
#pragma unroll
    for (int sp = 0; sp < 6; ++sp) {
      const f16x8 af = *(const f16x8*)(abase + j * 6144 + sp * 1024);
      const f16x4 alo = __builtin_shufflevector(af, af, 0, 1, 2, 3);
      const f16x4 ahi = __builtin_shufflevector(af, af, 4, 5, 6, 7);
      const int c0 = 2 * sp, c1 = 2 * sp + 1;
      if (c0 == 0)      acc = mfma16(alo, st0, acc);
      else if (c0 == 2) acc = mfma16(alo, stc, acc);
      else              acc = mfma16(alo, as_f16x4(msgc[c0 - 3]), acc);
      if (c1 == 1)      acc = mfma16(ahi, st1, acc);
      else              acc = mfma16(ahi, as_f16x4(msgc[c1 - 3]), acc);
    }
    f16x4 h;
#pragma unroll
    for (int r = 0; r < 4; ++r)
      h[r] = (_Float16)fmaxf(acc[r], 0.f);
    if (P) msg[O][j] = as_u64(h); else msg[j][O] = as_u64(h);
  }
}

template<int P, int O>
__device__ __forceinline__ void do_step_layer(int base, const unsigned char* __restrict__ ws,
    unsigned char* bufA, unsigned char* bufB, u64 (&msg)[9][9],
    u64 sb, u32 sb8, f16x4 stc, int lane, int tid)
{
  const int step = base + P * 9 + O;
  asm volatile("s_waitcnt vmcnt(0)" ::: "memory");
  __syncthreads();
  stage_n<256>(ws + (size_t)step * STEP_BYTES + PHA_SZ, bufB, PHB_SZ, tid);
  f16x4 st0, st1;
  {
    const u32 byt = (O < 8) ? ((u32)(sb >> (O * 8)) & 0xFFu) : sb8;
#pragma unroll
    for (int e = 0; e < 4; ++e) {
      st0[e] = (_Float16)(float)((byt >> e) & 1u);
      st1[e] = (_Float16)(float)((byt >> (4 + e)) & 1u);
    }
  }
  u64 msgc[9];
#pragma unroll
  for (int i = 0; i < 9; ++i)
    msgc[i] = P ? msg[O][i] : msg[i][O];
  jt_range<P, O, 0, 5, 0>(bufA, msg, msgc, st0, st1, stc, lane);
  asm volatile("s_waitcnt vmcnt(0)" ::: "memory");
  __syncthreads();
  if (step + 1 < 54)
    stage_n<256>(ws + (size_t)(step + 1) * STEP_BYTES, bufA, PHA_SZ, tid);
  else
    stage_n<256>(ws + WS_LAYER, bufA, CPA_SZ, tid);
  jt_range<P, O, 5, 9, PHA_SZ>(bufB, msg, msgc, st0, st1, stc, lane);
}

__global__ __launch_bounds__(256, 1) void mix_main(
    const float* __restrict__ mask, const float* __restrict__ board,
    const float* __restrict__ common_b, const float* __restrict__ wdl_w,
    const float* __restrict__ wdl_b, const unsigned char* __restrict__ ws,
    float* __restrict__ out, int Bt)
{
  extern __shared__ unsigned char lds[];
  const int tid = threadIdx.x;
  const int lane = tid & 63;
  const int wid = tid >> 6;
  const int s15 = lane & 15, hq = lane >> 4;
  const int b0 = blockIdx.x * 64 + wid * 16;
  unsigned char* bufA = lds;
  unsigned char* bufB = lds + PHA_SZ;

  stage_n<256>(ws, bufA, PHA_SZ, tid);

  u64 msg[9][9];
#pragma unroll
  for (int a = 0; a < 9; ++a)
#pragma unroll
    for (int b = 0; b < 9; ++b) msg[a][b] = 0ull;

  u64 sb = 0ull;
  u32 sb8 = 0u;
  {
    const int b = b0 + s15;
#pragma unroll
    for (int o = 0; o < 9; ++o)
#pragma unroll
      for (int e = 0; e < 4; ++e) {
        const u32 bit0 = static_feat(mask, board, b, o,      4 * hq + e) > 0.5f;
        const u32 bit1 = static_feat(mask, board, b, o, 16 + 4 * hq + e) > 0.5f;
        if (o < 8) sb |= ((u64)bit0 << (o * 8 + e)) | ((u64)bit1 << (o * 8 + 4 + e));
        else       sb8 |= (bit0 << e) | (bit1 << (4 + e));
      }
  }
  f16x4 stc;
  {
    const int b = b0 + s15;
#pragma unroll
    for (int e = 0; e < 4; ++e) {
      const int kidx = 32 + 4 * hq + e;
      stc[e] = (_Float16)((kidx == 45) ? 1.f : static_feat(mask, board, b, 0, kidx));
    }
  }

#define DO_POS(P, O) do_step_layer<P, O>(base, ws, bufA, bufB, msg, sb, sb8, stc, lane, tid);
  for (int dp = 0; dp < 3; ++dp) {
    const int base = dp * 18;
    DO_POS(0,0) DO_POS(0,1) DO_POS(0,2) DO_POS(0,3) DO_POS(0,4)
    DO_POS(0,5) DO_POS(0,6) DO_POS(0,7) DO_POS(0,8)
    DO_POS(1,0) DO_POS(1,1) DO_POS(1,2) DO_POS(1,3) DO_POS(1,4)
    DO_POS(1,5) DO_POS(1,6) DO_POS(1,7) DO_POS(1,8)
  }
#undef DO_POS

  float pw[3] = {0.f, 0.f, 0.f};
  for (int mt = 0; mt < 10; ++mt) {
    asm volatile("s_waitcnt vmcnt(0)" ::: "memory");
    __syncthreads();
    stage_n<256>(ws + WS_LAYER + (size_t)mt * CMN_STRIDE + CPA_SZ, bufB, CPB_SZ, tid);
    f32x4 a0 = 0.f;
#pragma unroll
    for (int i = 0; i < 5; ++i) {
      const unsigned char* base = bufA + i * 4608;
#pragma unroll
      for (int p = 0; p < 4; ++p) {
        const f16x8 af = *(const f16x8*)(base + p * 1024 + (size_t)lane * 16);
        const f16x4 alo = __builtin_shufflevector(af, af, 0, 1, 2, 3);
        const f16x4 ahi = __builtin_shufflevector(af, af, 4, 5, 6, 7);
        a0 = mfma16(alo, as_f16x4(msg[i][2 * p]),     a0);
        a0 = mfma16(ahi, as_f16x4(msg[i][2 * p + 1]), a0);
      }
      const f16x4 al = *(const f16x4*)(bufA + i * 4608 + 4096 + (size_t)lane * 8);
      a0 = mfma16(al, as_f16x4(msg[i][8]), a0);
    }
    asm volatile("s_waitcnt vmcnt(0)" ::: "memory");
    __syncthreads();
    if (mt + 1 < 10)
      stage_n<256>(ws + WS_LAYER + (size_t)(mt + 1) * CMN_STRIDE, bufA, CPA_SZ, tid);
#pragma unroll
    for (int i = 5; i < 9; ++i) {
      const unsigned char* base = bufB + i * 4608 - CPA_SZ;
#pragma unroll
      for (int p = 0; p < 4; ++p) {
        const f16x8 af = *(const f16x8*)(base + p * 1024 + (size_t)lane * 16);
        const f16x4 alo = __builtin_shufflevector(af, af, 0, 1, 2, 3);
        const f16x4 ahi = __builtin_shufflevector(af, af, 4, 5, 6, 7);
        a0 = mfma16(alo, as_f16x4(msg[i][2 * p]),     a0);
        a0 = mfma16(ahi, as_f16x4(msg[i][2 * p + 1]), a0);
      }
      const f16x4 al = *(const f16x4*)(base + 4096 + (size_t)lane * 8);
      a0 = mfma16(al, as_f16x4(msg[i][8]), a0);
    }
#pragma unroll
    for (int r = 0; r < 4; ++r) {
      const int c = mt * 16 + 4 * hq + r;
      const float bias = (c < 145) ? common_b[c] : 0.f;
      const float v0 = a0[r] + bias;
      if (c < 81) {
        out[(size_t)3 * Bt + (size_t)(b0 + s15) * 81 + c] = v0;
      } else if (c < 145) {
        const float h0 = fmaxf(v0, 0.f);
        const int cc = c - 81;
#pragma unroll
        for (int w = 0; w < 3; ++w)
          pw[w] += h0 * wdl_w[cc * 3 + w];
      }
    }
  }
#pragma unroll
  for (int w = 0; w < 3; ++w) {
    float v0 = pw[w];
    v0 += __shfl_xor(v0, 16, 64); v0 += __shfl_xor(v0, 32, 64);
    if (hq == 0)
      out[(size_t)(b0 + s15) * 3 + w] = v0 + wdl_b[w];
  }
}

// ===========================================================================
// SHARED / FUSED PROLOGUES (r10-proven layouts)
// ===========================================================================

__global__ __launch_bounds__(256) void conv_layer_w(const float* __restrict__ lw,
                                                    const float* __restrict__ lb,
                                                    unsigned char* __restrict__ dst) {
  const int gid = blockIdx.x * 256 + threadIdx.x;
  if (gid >= 54 * 9 * 6 * 64) return;
  const int lane = gid & 63;
  const int t = gid >> 6;
  const int kp = t % 6, t2 = t / 6;
  const int jp = t2 % 9, dop = t2 / 9;
  const int m = lane & 15, hq = lane >> 4;
  unsigned short v[8];
#pragma unroll
  for (int e = 0; e < 8; ++e) {
    const int kc = kp * 2 + (e >> 2);
    const int kidx = kc * 16 + 4 * hq + (e & 3);
    float f = 0.f;
    if (kidx < 45)        f = lw[((size_t)dop * 189 + kidx) * 144 + jp * 16 + m];
    else if (kidx == 45)  f = lb[(size_t)dop * 144 + jp * 16 + m];
    else if (kidx >= 48)  f = lw[((size_t)dop * 189 + (kidx - 3)) * 144 + jp * 16 + m];
    v[e] = f2h(f);
  }
  const u32 w0 = (u32)v[0] | ((u32)v[1] << 16);
  const u32 w1 = (u32)v[2] | ((u32)v[3] << 16);
  const u32 w2 = (u32)v[4] | ((u32)v[5] << 16);
  const u32 w3 = (u32)v[6] | ((u32)v[7] << 16);
  *(uint4*)(dst + (size_t)gid * 16) = make_uint4(w0, w1, w2, w3);
}

__global__ __launch_bounds__(256) void conv_common_w(const float* __restrict__ cw,
                                                     unsigned char* __restrict__ dst) {
  const int gid = blockIdx.x * 256 + threadIdx.x;
  const int NPAIR = 10 * 36 * 64;
  if (gid < NPAIR) {
    const int lane = gid & 63;
    const int t = gid >> 6;
    const int p = t % 4, t2 = t / 4;
    const int i = t2 % 9, mt = t2 / 9;
    const int m = lane & 15, hq = lane >> 4;
    const int c = mt * 16 + m;
    unsigned short v[8];
#pragma unroll
    for (int e = 0; e < 8; ++e) {
      const int ci = i * 9 + 2 * p + (e >> 2);
      const int k = ci * 16 + 4 * hq + (e & 3);
      v[e] = f2h((c < 145) ? cw[(size_t)k * 145 + c] : 0.f);
    }
    const u32 w0 = (u32)v[0] | ((u32)v[1] << 16);
    const u32 w1 = (u32)v[2] | ((u32)v[3] << 16);
    const u32 w2 = (u32)v[4] | ((u32)v[5] << 16);
    const u32 w3 = (u32)v[6] | ((u32)v[7] << 16);
    *(uint4*)(dst + (size_t)WS_LAYER + (size_t)mt * CMN_STRIDE + (size_t)i * 4608
              + (size_t)p * 1024 + (size_t)lane * 16) = make_uint4(w0, w1, w2, w3);
  } else if (gid < NPAIR + 10 * 9 * 64) {
    const int g = gid - NPAIR;
    const int lane = g & 63;
    const int t = g >> 6;
    const int i = t % 9, mt = t / 9;
    const int m = lane & 15, hq = lane >> 4;
    const int c = mt * 16 + m;
    unsigned short v[4];
#pragma unroll
    for (int e = 0; e < 4; ++e) {
      const int k = (i * 9 + 8) * 16 + 4 * hq + e;
      v[e] = f2h((c < 145) ? cw[(size_t)k * 145 + c] : 0.f);
    }
    const u32 w0 = (u32)v[0] | ((u32)v[1] << 16);
    const u32 w1 = (u32)v[2] | ((u32)v[3] << 16);
    *(uint2*)(dst + (size_t)WS_LAYER + (size_t)mt * CMN_STRIDE + (size_t)i * 4608
              + 4096 + (size_t)lane * 8) = make_uint2(w0, w1);
  }
}

// ===========================================================================

extern "C" void kernel_launch(void* const* d_in, const int* in_sizes, int n_in,
                              void* d_out, int out_size, void* d_ws, size_t ws_size,
                              hipStream_t stream) {
  const float* mask     = (const float*)d_in[0];
  const float* board    = (const float*)d_in[1];
  const float* layer_w  = (const float*)d_in[2];
  const float* layer_b  = (const float*)d_in[3];
  const float* common_w = (const float*)d_in[4];
  const float* common_b = (const float*)d_in[5];
  const float* wdl_w    = (const float*)d_in[6];
  const float* wdl_b    = (const float*)d_in[7];
  float* out = (float*)d_out;
  unsigned char* ws = (unsigned char*)d_ws;
  const int Bt = in_sizes[0] / 81;   // 65536

  // ws layout (CW region shared by both paths at WS_LAYER, layouts differ)
  const size_t WS_CW_OFF   = (size_t)WS_LAYER;
  const size_t WS_STAT_OFF = WS_CW_OFF + (size_t)9 * CSL_SZ;
  const size_t WS_MSG_OFF  = WS_STAT_OFF + (size_t)19 * Bt * 32;
  const size_t WS_NEED     = WS_MSG_OFF + (size_t)81 * Bt * 32;

  hipLaunchKernelGGL(conv_layer_w, dim3((54 * 9 * 6 * 64) / 256), dim3(256), 0, stream,
                     layer_w, layer_b, ws);

  if (ws_size >= WS_NEED) {
    unsigned char* stat = ws + WS_STAT_OFF;
    unsigned char* msgp = ws + WS_MSG_OFF;

    hipLaunchKernelGGL(conv_common_w2, dim3((10 * (36 + 9) * 64 + 255) / 256), dim3(256),
                       0, stream, common_w, ws + WS_CW_OFF);
    hipLaunchKernelGGL(conv_static, dim3(Bt / 16), dim3(256), 0, stream,
                       mask, board, stat, Bt);

    const dim3 lgrid(Bt / 256, 9);
    hipLaunchKernelGGL((layer_step<0, 1>), lgrid, dim3(512), 0, stream, ws, stat, msgp, 0, Bt);
    hipLaunchKernelGGL((layer_step<1, 0>), lgrid, dim3(512), 0, stream, ws, stat, msgp, 1, Bt);
    hipLaunchKernelGGL((layer_step<0, 0>), lgrid, dim3(512), 0, stream, ws, stat, msgp, 2, Bt);
    hipLaunchKernelGGL((layer_step<1, 0>), lgrid, dim3(512), 0, stream, ws, stat, msgp, 3, Bt);
    hipLaunchKernelGGL((layer_step<0, 0>), lgrid, dim3(512), 0, stream, ws, stat, msgp, 4, Bt);
    hipLaunchKernelGGL((layer_step<1, 0>), lgrid, dim3(512), 0, stream, ws, stat, msgp, 5, Bt);

    hipLaunchKernelGGL(common_unf, dim3(Bt / 128), dim3(256), 0, stream,
                       ws + WS_CW_OFF, msgp, common_b, wdl_w, wdl_b, out, Bt);
  } else {
    hipLaunchKernelGGL(conv_common_w, dim3((10 * (36 + 9) * 64 + 255) / 256), dim3(256),
                       0, stream, common_w, ws);
    (void)hipFuncSetAttribute((const void*)mix_main,
                              hipFuncAttributeMaxDynamicSharedMemorySize, LDS_TOTAL);
    hipLaunchKernelGGL(mix_main, dim3(Bt / 64), dim3(256), LDS_TOTAL, stream,
                       mask, board, common_b, wdl_w, wdl_b, ws, out, Bt);
  }
}